// Round 8
// baseline (592.194 us; speedup 1.0000x reference)
//
#include <hip/hip_runtime.h>
#include <hip/hip_cooperative_groups.h>
#include <math.h>

namespace cg = cooperative_groups;

// Capsule routing, no u_hat materialization.
// Round 8: ONE cooperative kernel (512 blocks, 2/CU co-resident) with
// grid.sync() between phases — eliminates 5 kernel launches + drains.
// Phase bodies are VERBATIM the proven versions (R2 k_route = best measured
// 43 µs; original k_ot/k_sumu). Host falls back to the 6-launch path if
// cooperative launch is rejected. Workspace: 18.5 MB (proven envelope).

#define B   64
#define IN  1024
#define ID  256
#define NC  32
#define DC  64
#define RTILE 128   // 8 chunks

// ---------------------------------------------------------------------------
// o/t phase body (exact k_ot): per (b,n):
//   s = reduced partials; o = W_n s;
//   mode 0/1: normalize o, dst = W_n^T o_norm (t);  mode 2: squash(o) -> dst (out)
__device__ __forceinline__ void ot_body(const float* __restrict__ W,
                                        const float* __restrict__ src,
                                        float* __restrict__ dst,
                                        const int mode, const int b, const int n,
                                        const int tid,
                                        float* s_lds, float* o_lds, float* on_lds) {
    float sv = 0.f;
    if (mode == 0) {
#pragma unroll
        for (int c = 0; c < 8; ++c) sv += src[(c * B + b) * ID + tid];
        sv *= (1.0f / NC);
    } else {
#pragma unroll
        for (int c = 0; c < 8; ++c) sv += src[((size_t)(c * B + b) * NC + n) * ID + tid];
    }
    s_lds[tid] = sv;
    __syncthreads();

    const int wave = tid >> 6, lane = tid & 63;
    const float* Wn = W + (size_t)n * DC * ID;
#pragma unroll 4
    for (int r = 0; r < 16; ++r) {
        const int d = wave * 16 + r;
        const float* wrow = Wn + (size_t)d * ID;
        float p = wrow[lane]        * s_lds[lane]
                + wrow[lane + 64]   * s_lds[lane + 64]
                + wrow[lane + 128]  * s_lds[lane + 128]
                + wrow[lane + 192]  * s_lds[lane + 192];
#pragma unroll
        for (int off = 32; off > 0; off >>= 1) p += __shfl_down(p, off);
        if (lane == 0) o_lds[d] = p;
    }
    __syncthreads();

    if (mode == 2) {
        if (tid < DC) {
            float v = o_lds[tid];
            float sq = v * v;
#pragma unroll
            for (int off = 32; off > 0; off >>= 1) sq += __shfl_down(sq, off);
            sq = __shfl(sq, 0) + 1e-7f;
            const float sc = sqrtf(sq) / (0.5f + sq);
            dst[(size_t)(b * NC + n) * DC + tid] = v * sc;
        }
        return;
    }

    if (tid < DC) {
        float v = o_lds[tid];
        float sq = v * v;
#pragma unroll
        for (int off = 32; off > 0; off >>= 1) sq += __shfl_down(sq, off);
        sq = __shfl(sq, 0);
        const float inv = 1.0f / fmaxf(sqrtf(sq), 1e-12f);
        on_lds[tid] = v * inv;
    }
    __syncthreads();

    float acc = 0.f;
    const float* wc = Wn + tid;
#pragma unroll 8
    for (int d = 0; d < DC; ++d) acc += wc[(size_t)d * ID] * on_lds[d];
    dst[((size_t)b * NC + n) * ID + tid] = acc;
}

// ---------------------------------------------------------------------------
// Fused routing step body (exact R2 k_route, the measured-best 43 µs version):
//   logits (LDS) -> softmax -> weighted aggregation -> sp[it][b][n][d]
// smem carve: Ts[256][36] @0 (9216) | Us[16][132] @9216 (2112) | cl[128][36] @11328 (4608)
__device__ __forceinline__ void route_body(const float* __restrict__ u,
                                           const float* __restrict__ t,
                                           float* __restrict__ sp,
                                           const int it, const int b, const int tid,
                                           float* smem) {
    float (*Ts)[36]  = (float(*)[36])smem;
    float (*Us)[132] = (float(*)[132])(smem + 9216);
    float (*cl)[36]  = (float(*)[36])(smem + 11328);

    const float* ub = u + ((size_t)b * IN + (size_t)it * RTILE) * ID;
    const float* tb = t + (size_t)b * NC * ID;

    // stage Ts (one-time): thread=k, loop n; guarded by kc-loop's first barrier
#pragma unroll
    for (int n = 0; n < NC; ++n) Ts[tid][n] = tb[(size_t)n * ID + tid];

    const int q = tid >> 3;   // i-group: i0 = q*4
    const int r = tid & 7;    // n-group: n0 = r*4
    float acc[4][4] = {{0.f}};

    for (int kc = 0; kc < ID / 16; ++kc) {
        __syncthreads();   // Ts ready (first iter) / prior chunk consumed
#pragma unroll
        for (int rep = 0; rep < 2; ++rep) {
            const int f = tid + rep * 256;
            const int i = f >> 2, c4 = f & 3;
            const float4 v = *(const float4*)(ub + (size_t)i * ID + kc * 16 + c4 * 4);
            Us[c4 * 4 + 0][i] = v.x;
            Us[c4 * 4 + 1][i] = v.y;
            Us[c4 * 4 + 2][i] = v.z;
            Us[c4 * 4 + 3][i] = v.w;
        }
        __syncthreads();
#pragma unroll
        for (int k = 0; k < 16; ++k) {
            const float4 a4 = *(const float4*)&Us[k][q * 4];
            const float4 b4 = *(const float4*)&Ts[kc * 16 + k][r * 4];
            const float av[4] = {a4.x, a4.y, a4.z, a4.w};
            const float bv[4] = {b4.x, b4.y, b4.z, b4.w};
#pragma unroll
            for (int ii = 0; ii < 4; ++ii)
#pragma unroll
                for (int jj = 0; jj < 4; ++jj) acc[ii][jj] += av[ii] * bv[jj];
        }
    }

    // logits -> cl (disjoint from Ts/Us regions)
#pragma unroll
    for (int ii = 0; ii < 4; ++ii)
        *(float4*)&cl[q * 4 + ii][r * 4] =
            make_float4(acc[ii][0], acc[ii][1], acc[ii][2], acc[ii][3]);
    __syncthreads();

    // softmax over 32 n; 2 threads per i (16 n each)
    {
        const int i = tid >> 1, half = tid & 1;
        float v[16];
#pragma unroll
        for (int j = 0; j < 16; ++j) v[j] = cl[i][half * 16 + j];
        float mx = v[0];
#pragma unroll
        for (int j = 1; j < 16; ++j) mx = fmaxf(mx, v[j]);
        mx = fmaxf(mx, __shfl_xor(mx, 1));
        float sum = 0.f;
#pragma unroll
        for (int j = 0; j < 16; ++j) { v[j] = __expf(v[j] - mx); sum += v[j]; }
        sum += __shfl_xor(sum, 1);
        const float inv = 1.0f / sum;
#pragma unroll
        for (int j = 0; j < 16; ++j) cl[i][half * 16 + j] = v[j] * inv;
    }
    __syncthreads();

    // weighted aggregation (u tile re-read, L2-hot)
    const int d4 = tid & 63;
    const int ng = tid >> 6;
    float a2[8][4] = {{0.f}};
    const float* ur = ub + d4 * 4;
#pragma unroll 4
    for (int i = 0; i < RTILE; ++i) {
        const float4 uv = *(const float4*)(ur + (size_t)i * ID);
        const float4 c0 = *(const float4*)&cl[i][ng * 8];
        const float4 c1 = *(const float4*)&cl[i][ng * 8 + 4];
        const float cv[8] = {c0.x, c0.y, c0.z, c0.w, c1.x, c1.y, c1.z, c1.w};
        const float uvv[4] = {uv.x, uv.y, uv.z, uv.w};
#pragma unroll
        for (int j = 0; j < 8; ++j)
#pragma unroll
            for (int x = 0; x < 4; ++x) a2[j][x] += cv[j] * uvv[x];
    }

    float* spb = sp + (size_t)(it * B + b) * NC * ID;
#pragma unroll
    for (int j = 0; j < 8; ++j)
        *(float4*)&spb[(size_t)(ng * 8 + j) * ID + d4 * 4] =
            make_float4(a2[j][0], a2[j][1], a2[j][2], a2[j][3]);
}

// ---------------------------------------------------------------------------
// The whole routing as ONE cooperative kernel. Grid 512 = 8 it-chunks x 64 b,
// 256 threads, static LDS 63.75 KB -> 2 blocks/CU co-resident (guaranteed).
__global__ __launch_bounds__(256, 2) void k_caps(const float* __restrict__ u,
                                                 const float* __restrict__ W,
                                                 float* __restrict__ t,
                                                 float* __restrict__ sp,
                                                 float* __restrict__ sp0,
                                                 float* __restrict__ out) {
    cg::grid_group grid = cg::this_grid();
    const int bx = blockIdx.x;
    const int b  = bx & (B - 1);
    const int it = bx >> 6;
    const int tid = threadIdx.x;
    __shared__ __align__(16) float smem[15936];   // 63.75 KB, phase-overlaid

    // phase A: sp0[it][b][d] = sum over this i-chunk of u[b][i][d]  (k_sumu)
    {
        const float* up = u + ((size_t)b * IN + (size_t)it * RTILE) * ID + tid;
        float a = 0.f;
#pragma unroll 8
        for (int i = 0; i < RTILE; ++i) a += up[(size_t)i * ID];
        sp0[(it * B + b) * ID + tid] = a;
    }
    grid.sync();

    for (int iter = 0; iter < 3; ++iter) {
        // o/t phase: 2048 (b,n) tasks over 512 blocks = 4 per block
        const float* src = (iter == 0) ? sp0 : sp;
        float* dst = (iter == 2) ? out : t;
#pragma unroll 1
        for (int j = 0; j < 4; ++j) {
            const int task = bx * 4 + j;
            ot_body(W, src, dst, iter, task >> 5, task & (NC - 1), tid,
                    smem, smem + 256, smem + 320);
            __syncthreads();   // task separation (LDS reuse)
        }
        if (iter == 2) break;
        grid.sync();           // t visible to all blocks
        route_body(u, t, sp, it, b, tid, smem);
        grid.sync();           // sp visible to all blocks
    }
}

// ---------------------------------------------------------------------------
// Fallback standalone kernels (proven 6-launch path), same bodies.
__global__ __launch_bounds__(256) void k_sumu(const float* __restrict__ u,
                                              float* __restrict__ sp0) {
    const int c = blockIdx.x, b = blockIdx.y;
    const int d = threadIdx.x;
    const float* up = u + ((size_t)b * IN + (size_t)c * RTILE) * ID + d;
    float acc = 0.f;
#pragma unroll 8
    for (int i = 0; i < RTILE; ++i) acc += up[(size_t)i * ID];
    sp0[(c * B + b) * ID + d] = acc;
}

__global__ __launch_bounds__(256) void k_ot(const float* __restrict__ W,
                                            const float* __restrict__ src,
                                            float* __restrict__ tout,
                                            const int mode) {
    __shared__ float smem[384];
    ot_body(W, src, tout, mode, blockIdx.x / NC, blockIdx.x % NC, threadIdx.x,
            smem, smem + 256, smem + 320);
}

__global__ __launch_bounds__(256) void k_route(const float* __restrict__ u,
                                               const float* __restrict__ t,
                                               float* __restrict__ sp) {
    __shared__ __align__(16) float smem[15936];
    route_body(u, t, sp, blockIdx.x, blockIdx.y, threadIdx.x, smem);
}

// ---------------------------------------------------------------------------
extern "C" void kernel_launch(void* const* d_in, const int* in_sizes, int n_in,
                              void* d_out, int out_size, void* d_ws, size_t ws_size,
                              hipStream_t stream) {
    const float* u = (const float*)d_in[0];   // [B][IN][ID]
    const float* W = (const float*)d_in[1];   // [NC*DC][ID]
    float* out = (float*)d_out;               // [B][NC][DC]

    float* ws  = (float*)d_ws;
    float* t   = ws;                                   // B*NC*ID      = 0.5M floats
    float* sp  = t + (size_t)B * NC * ID;              // 8*B*NC*ID    = 4M floats
    float* sp0 = sp + (size_t)8 * B * NC * ID;         // 8*B*ID       = 128K floats

    void* args[] = {(void*)&u, (void*)&W, (void*)&t, (void*)&sp, (void*)&sp0, (void*)&out};
    const hipError_t err = hipLaunchCooperativeKernel(
        (const void*)k_caps, dim3(B * (IN / RTILE)), dim3(256), args, 0, stream);

    if (err != hipSuccess) {
        // proven 6-launch path
        k_sumu <<<dim3(IN / RTILE, B), dim3(256), 0, stream>>>(u, sp0);
        k_ot   <<<dim3(B * NC), dim3(256), 0, stream>>>(W, sp0, t, 0);
        k_route<<<dim3(IN / RTILE, B), dim3(256), 0, stream>>>(u, t, sp);
        k_ot   <<<dim3(B * NC), dim3(256), 0, stream>>>(W, sp, t, 1);
        k_route<<<dim3(IN / RTILE, B), dim3(256), 0, stream>>>(u, t, sp);
        k_ot   <<<dim3(B * NC), dim3(256), 0, stream>>>(W, sp, out, 2);
    }
}

// Round 10
// 204.993 us; speedup vs baseline: 2.8888x; 2.8888x over previous
//
#include <hip/hip_runtime.h>
#include <math.h>

// Capsule routing, no u_hat materialization.
// Round 10: IDENTICAL resubmit of round 9 (container infra died twice; source
// audits clean — same precedent as R1->R2 which then measured fine).
// Structure: R2's proven 6-kernel pipeline; single change vs R2 is k_ot's
// row-dots parallelized (64 x 4-lane groups, f4 loads, 2 shuffles/thread
// instead of 96) and all-lane norm. Workspace 18.5 MB (proven envelope).

#define B   64
#define IN  1024
#define ID  256
#define NC  32
#define DC  64

// ---------------------------------------------------------------------------
// sp0[c][b][d] = sum over i-chunk c of u[b][i][d]   (8 chunks of 128 i)
__global__ __launch_bounds__(256) void k_sumu(const float* __restrict__ u,
                                              float* __restrict__ sp0) {
    const int c = blockIdx.x, b = blockIdx.y;
    const int d = threadIdx.x;
    const float* up = u + ((size_t)b * IN + (size_t)c * (IN / 8)) * ID + d;
    float acc = 0.f;
#pragma unroll 8
    for (int i = 0; i < IN / 8; ++i) acc += up[(size_t)i * ID];
    sp0[(c * B + b) * ID + d] = acc;
}

// ---------------------------------------------------------------------------
// Per (b,n): s = (reduced partials); o = W_n s ; then
//   mode 0: s from sp0 (uniform c=1/32), normalize o, t = W_n^T o_norm
//   mode 1: s from sp,                  normalize o, t = W_n^T o_norm
//   mode 2: s from sp, squash(o) -> out
// o-rows computed by 64 concurrent 4-lane groups (f4 loads, 2 shfl each).
__global__ __launch_bounds__(256) void k_ot(const float* __restrict__ W,
                                            const float* __restrict__ src,
                                            float* __restrict__ tout,
                                            const int mode) {
    const int bn = blockIdx.x;
    const int b = bn / NC, n = bn % NC;
    __shared__ __align__(16) float s_lds[ID];
    __shared__ float o_lds[DC];
    __shared__ float red[DC];
    const int tid = threadIdx.x;

    // reduce partial sums into s_lds (coalesced)
    float sv = 0.f;
    if (mode == 0) {
#pragma unroll
        for (int c = 0; c < 8; ++c) sv += src[(c * B + b) * ID + tid];
        sv *= (1.0f / NC);
    } else {
#pragma unroll
        for (int c = 0; c < 8; ++c) sv += src[((size_t)(c * B + b) * NC + n) * ID + tid];
    }
    s_lds[tid] = sv;
    __syncthreads();

    // o[d] = dot(W[n*DC+d, :], s) — group g=tid>>2 owns row d=g; lane j=tid&3
    // covers k in f4 chunks (kk*4+j)*4.  s_lds reads broadcast across groups.
    const int g = tid >> 2, j = tid & 3;
    const float* wrow = W + ((size_t)n * DC + g) * ID;
    float p = 0.f;
#pragma unroll
    for (int kk = 0; kk < 16; ++kk) {
        const int k = (kk * 4 + j) * 4;
        const float4 wv = *(const float4*)(wrow + k);
        const float4 s4 = *(const float4*)(s_lds + k);
        p += wv.x * s4.x + wv.y * s4.y + wv.z * s4.z + wv.w * s4.w;
    }
    p += __shfl_xor(p, 1);
    p += __shfl_xor(p, 2);
    if (j == 0) { o_lds[g] = p; red[g] = p * p; }
    __syncthreads();

    // wave 0: ||o||^2 over the 64 rows, then scale o in place
    if (tid < DC) {
        float q = red[tid];
#pragma unroll
        for (int off = 32; off > 0; off >>= 1) q += __shfl_down(q, off);
        q = __shfl(q, 0);
        if (mode == 2) {
            const float sq = q + 1e-7f;
            const float sc = sqrtf(sq) / (0.5f + sq);
            tout[(size_t)(b * NC + n) * DC + tid] = o_lds[tid] * sc;
        } else {
            const float inv = 1.0f / fmaxf(sqrtf(q), 1e-12f);
            o_lds[tid] *= inv;     // on = normalized o
        }
    }
    if (mode == 2) return;
    __syncthreads();

    // t[k] = sum_d W[n*DC+d, k] * on[d]   — thread per k, coalesced column walk
    float acc = 0.f;
    const float* wc = W + (size_t)n * DC * ID + tid;
#pragma unroll 8
    for (int d = 0; d < DC; ++d) acc += wc[(size_t)d * ID] * o_lds[d];
    tout[((size_t)b * NC + n) * ID + tid] = acc;
}

// ---------------------------------------------------------------------------
// Fused per-iteration routing step (VERBATIM R2 body — measured best, 43.1 µs):
//   logits[i][n] = sum_d u[b,i,d] * t[b,n,d]   (in LDS, never to HBM)
//   c = softmax_n(logits)
//   sp[it][b][n][d] = sum_{i in tile} c[i][n] * u[b,i,d]
#define RTILE 128
__global__ __launch_bounds__(256) void k_route(const float* __restrict__ u,
                                               const float* __restrict__ t,
                                               float* __restrict__ sp) {
    const int it = blockIdx.x, b = blockIdx.y;
    const int iBase = it * RTILE;
    __shared__ float Ts[ID][36];      // t[b] transposed: Ts[k][n]  (36.9 KB)
    __shared__ float Us[16][132];     // u chunk transposed: Us[k][i] (8.4 KB)
    __shared__ float cl[RTILE][36];   // logits -> softmax coeffs   (18.4 KB)
    const int tid = threadIdx.x;

    // load full Ts (one-time): thread=k, loop n. Global coalesced.
    {
        const float* tb = t + (size_t)b * NC * ID;
#pragma unroll
        for (int n = 0; n < NC; ++n) Ts[tid][n] = tb[(size_t)n * ID + tid];
    }

    // ---- phase 1: logits ----
    const int q = tid >> 3;   // i-thread: i0 = q*4
    const int r = tid & 7;    // n-thread: n0 = r*4
    float acc[4][4] = {{0.f}};
    const float* ub = u + ((size_t)b * IN + iBase) * ID;

    for (int kc = 0; kc < ID / 16; ++kc) {
        __syncthreads();   // Ts ready (first iter) / prior chunk consumed
#pragma unroll
        for (int rep = 0; rep < 2; ++rep) {
            const int f = tid + rep * 256;
            const int i = f >> 2, c4 = f & 3;
            const float4 v = *(const float4*)(ub + (size_t)i * ID + kc * 16 + c4 * 4);
            Us[c4 * 4 + 0][i] = v.x;
            Us[c4 * 4 + 1][i] = v.y;
            Us[c4 * 4 + 2][i] = v.z;
            Us[c4 * 4 + 3][i] = v.w;
        }
        __syncthreads();
#pragma unroll
        for (int k = 0; k < 16; ++k) {
            const float4 a4 = *(const float4*)&Us[k][q * 4];
            const float4 b4 = *(const float4*)&Ts[kc * 16 + k][r * 4];
            const float av[4] = {a4.x, a4.y, a4.z, a4.w};
            const float bv[4] = {b4.x, b4.y, b4.z, b4.w};
#pragma unroll
            for (int ii = 0; ii < 4; ++ii)
#pragma unroll
                for (int jj = 0; jj < 4; ++jj) acc[ii][jj] += av[ii] * bv[jj];
        }
    }

    // logits -> LDS
#pragma unroll
    for (int ii = 0; ii < 4; ++ii)
        *(float4*)&cl[q * 4 + ii][r * 4] =
            make_float4(acc[ii][0], acc[ii][1], acc[ii][2], acc[ii][3]);
    __syncthreads();

    // ---- phase 2: softmax over 32 n; 2 threads per i (16 n each) ----
    {
        const int i = tid >> 1, half = tid & 1;
        float v[16];
#pragma unroll
        for (int j = 0; j < 16; ++j) v[j] = cl[i][half * 16 + j];
        float mx = v[0];
#pragma unroll
        for (int j = 1; j < 16; ++j) mx = fmaxf(mx, v[j]);
        mx = fmaxf(mx, __shfl_xor(mx, 1));
        float sum = 0.f;
#pragma unroll
        for (int j = 0; j < 16; ++j) { v[j] = __expf(v[j] - mx); sum += v[j]; }
        sum += __shfl_xor(sum, 1);
        const float inv = 1.0f / sum;
#pragma unroll
        for (int j = 0; j < 16; ++j) cl[i][half * 16 + j] = v[j] * inv;
    }
    __syncthreads();

    // ---- phase 3: weighted aggregation (u tile re-read, L2-hot) ----
    const int d4 = tid & 63;       // float4 index into ID
    const int ng = tid >> 6;       // n base = ng*8 (wave-uniform -> LDS broadcast)
    float a2[8][4] = {{0.f}};
    const float* ur = ub + d4 * 4;
#pragma unroll 4
    for (int i = 0; i < RTILE; ++i) {
        const float4 uv = *(const float4*)(ur + (size_t)i * ID);
        const float4 c0 = *(const float4*)&cl[i][ng * 8];
        const float4 c1 = *(const float4*)&cl[i][ng * 8 + 4];
        const float cv[8] = {c0.x, c0.y, c0.z, c0.w, c1.x, c1.y, c1.z, c1.w};
        const float uvv[4] = {uv.x, uv.y, uv.z, uv.w};
#pragma unroll
        for (int j = 0; j < 8; ++j)
#pragma unroll
            for (int x = 0; x < 4; ++x) a2[j][x] += cv[j] * uvv[x];
    }

    float* spb = sp + (size_t)(it * B + b) * NC * ID;
#pragma unroll
    for (int j = 0; j < 8; ++j) {
        const int n = ng * 8 + j;
        *(float4*)&spb[(size_t)n * ID + d4 * 4] =
            make_float4(a2[j][0], a2[j][1], a2[j][2], a2[j][3]);
    }
}

// ---------------------------------------------------------------------------
extern "C" void kernel_launch(void* const* d_in, const int* in_sizes, int n_in,
                              void* d_out, int out_size, void* d_ws, size_t ws_size,
                              hipStream_t stream) {
    const float* u = (const float*)d_in[0];   // [B][IN][ID]
    const float* W = (const float*)d_in[1];   // [NC*DC][ID]
    float* out = (float*)d_out;               // [B][NC][DC]

    float* ws  = (float*)d_ws;
    float* t   = ws;                                   // B*NC*ID      = 0.5M floats
    float* sp  = t + (size_t)B * NC * ID;              // 8*B*NC*ID    = 4M floats
    float* sp0 = sp + (size_t)8 * B * NC * ID;         // 8*B*ID       = 128K floats

    const dim3 blk(256);

    // routing iteration 0 (c uniform = 1/32)
    k_sumu <<<dim3(8, B), blk, 0, stream>>>(u, sp0);
    k_ot   <<<dim3(B * NC), blk, 0, stream>>>(W, sp0, t, 0);
    // iteration 1 (logits + softmax + aggregate fused)
    k_route<<<dim3(IN / RTILE, B), blk, 0, stream>>>(u, t, sp);
    k_ot   <<<dim3(B * NC), blk, 0, stream>>>(W, sp, t, 1);
    // iteration 2
    k_route<<<dim3(IN / RTILE, B), blk, 0, stream>>>(u, t, sp);
    k_ot   <<<dim3(B * NC), blk, 0, stream>>>(W, sp, out, 2);
}

// Round 11
// 190.845 us; speedup vs baseline: 3.1030x; 1.0741x over previous
//
#include <hip/hip_runtime.h>
#include <math.h>

// Capsule routing, no u_hat materialization.
// Round 11: non-route kernels attacked. k_ot batched x4 over b (W_n panel
// loaded once per 4 tasks -> L2 traffic 268->67 MB/dispatch); k_sumu f4
// vectorized (16B/lane). k_route VERBATIM R2 (43.1 µs anchor, 5 variants
// failed to beat it). Workspace 18.5 MB (proven envelope).

#define B   64
#define IN  1024
#define ID  256
#define NC  32
#define DC  64

// ---------------------------------------------------------------------------
// sp0[c][b][d] = sum over i-chunk c of u[b][i][d]   (8 chunks of 128 i)
// f4 loads: lane reads 16 B, wave reads 1 KB contiguous (coalescing sweet spot).
__global__ __launch_bounds__(256) void k_sumu(const float* __restrict__ u,
                                              float* __restrict__ sp0) {
    const int c = blockIdx.x, b = blockIdx.y;
    const int tid = threadIdx.x;
    const int d4 = tid & 63, ig = tid >> 6;
    __shared__ float4 part[4][64];
    const float* up = u + ((size_t)b * IN + (size_t)c * (IN / 8) + ig) * ID + d4 * 4;
    float4 a = make_float4(0.f, 0.f, 0.f, 0.f);
#pragma unroll 8
    for (int i = 0; i < 32; ++i) {
        const float4 v = *(const float4*)(up + (size_t)i * 4 * ID);
        a.x += v.x; a.y += v.y; a.z += v.z; a.w += v.w;
    }
    part[ig][d4] = a;
    __syncthreads();
    if (tid < 64) {
        const float4 t0 = part[0][tid], t1 = part[1][tid];
        const float4 t2 = part[2][tid], t3 = part[3][tid];
        const float4 r = make_float4(t0.x + t1.x + t2.x + t3.x,
                                     t0.y + t1.y + t2.y + t3.y,
                                     t0.z + t1.z + t2.z + t3.z,
                                     t0.w + t1.w + t2.w + t3.w);
        *(float4*)&sp0[(size_t)(c * B + b) * ID + tid * 4] = r;
    }
}

// ---------------------------------------------------------------------------
// Batched o/t kernel: block = (n, bq) handles b in {bq, bq+16, bq+32, bq+48}.
// Per (b,n): s = reduced partials; o = W_n s ; then
//   mode 0/1: normalize o, t = W_n^T o_norm ;  mode 2: squash(o) -> out
// W_n element loaded ONCE serves 4 tasks (register reuse) -> L2 traffic /4.
__global__ __launch_bounds__(256) void k_ot(const float* __restrict__ W,
                                            const float* __restrict__ src,
                                            float* __restrict__ tout,
                                            const int mode) {
    const int n  = blockIdx.x & (NC - 1);
    const int bq = blockIdx.x >> 5;          // 0..15
    const int tid = threadIdx.x;
    __shared__ __align__(16) float s_lds[4][ID];
    __shared__ float o_lds[4][DC];
    __shared__ float red[4][DC];

    // reduce partial sums into s_lds for the 4 b's (coalesced)
#pragma unroll
    for (int m = 0; m < 4; ++m) {
        const int b = bq + m * 16;
        float sv = 0.f;
        if (mode == 0) {
#pragma unroll
            for (int c = 0; c < 8; ++c) sv += src[(size_t)(c * B + b) * ID + tid];
            sv *= (1.0f / NC);
        } else {
#pragma unroll
            for (int c = 0; c < 8; ++c)
                sv += src[((size_t)(c * B + b) * NC + n) * ID + tid];
        }
        s_lds[m][tid] = sv;
    }
    __syncthreads();

    // o[d] = dot(W[n*DC+d, :], s) — group g=tid>>2 owns row d=g; lane j=tid&3
    // covers k in f4 chunks. wv loaded once, feeds 4 tasks.
    const int g = tid >> 2, j = tid & 3;
    const float* wrow = W + ((size_t)n * DC + g) * ID;
    float p[4] = {0.f, 0.f, 0.f, 0.f};
#pragma unroll
    for (int kk = 0; kk < 16; ++kk) {
        const int k = (kk * 4 + j) * 4;
        const float4 wv = *(const float4*)(wrow + k);
#pragma unroll
        for (int m = 0; m < 4; ++m) {
            const float4 s4 = *(const float4*)(&s_lds[m][k]);
            p[m] += wv.x * s4.x + wv.y * s4.y + wv.z * s4.z + wv.w * s4.w;
        }
    }
#pragma unroll
    for (int m = 0; m < 4; ++m) {
        p[m] += __shfl_xor(p[m], 1);
        p[m] += __shfl_xor(p[m], 2);
    }
    if (j == 0) {
#pragma unroll
        for (int m = 0; m < 4; ++m) { o_lds[m][g] = p[m]; red[m][g] = p[m] * p[m]; }
    }
    __syncthreads();

    // wave w finishes task m=w: ||o||^2 reduce, then squash-store or scale
    const int w = tid >> 6, lane = tid & 63;
    {
        float q = red[w][lane];
#pragma unroll
        for (int off = 32; off > 0; off >>= 1) q += __shfl_down(q, off);
        q = __shfl(q, 0);
        if (mode == 2) {
            const float sq = q + 1e-7f;
            const float sc = sqrtf(sq) / (0.5f + sq);
            const int b = bq + w * 16;
            tout[(size_t)(b * NC + n) * DC + lane] = o_lds[w][lane] * sc;
        } else {
            const float inv = 1.0f / fmaxf(sqrtf(q), 1e-12f);
            o_lds[w][lane] *= inv;     // on = normalized o
        }
    }
    if (mode == 2) return;
    __syncthreads();

    // t[k] = sum_d W[n*DC+d, k] * on[d] — thread per k, coalesced column walk;
    // each W element feeds 4 tasks.
    float acc[4] = {0.f, 0.f, 0.f, 0.f};
    const float* wc = W + (size_t)n * DC * ID + tid;
#pragma unroll 8
    for (int d = 0; d < DC; ++d) {
        const float wv = wc[(size_t)d * ID];
#pragma unroll
        for (int m = 0; m < 4; ++m) acc[m] += wv * o_lds[m][d];
    }
#pragma unroll
    for (int m = 0; m < 4; ++m) {
        const int b = bq + m * 16;
        tout[((size_t)b * NC + n) * ID + tid] = acc[m];
    }
}

// ---------------------------------------------------------------------------
// Fused per-iteration routing step (VERBATIM R2 body — measured best, 43.1 µs):
//   logits[i][n] = sum_d u[b,i,d] * t[b,n,d]   (in LDS, never to HBM)
//   c = softmax_n(logits)
//   sp[it][b][n][d] = sum_{i in tile} c[i][n] * u[b,i,d]
#define RTILE 128
__global__ __launch_bounds__(256) void k_route(const float* __restrict__ u,
                                               const float* __restrict__ t,
                                               float* __restrict__ sp) {
    const int it = blockIdx.x, b = blockIdx.y;
    const int iBase = it * RTILE;
    __shared__ float Ts[ID][36];      // t[b] transposed: Ts[k][n]  (36.9 KB)
    __shared__ float Us[16][132];     // u chunk transposed: Us[k][i] (8.4 KB)
    __shared__ float cl[RTILE][36];   // logits -> softmax coeffs   (18.4 KB)
    const int tid = threadIdx.x;

    // load full Ts (one-time): thread=k, loop n. Global coalesced.
    {
        const float* tb = t + (size_t)b * NC * ID;
#pragma unroll
        for (int n = 0; n < NC; ++n) Ts[tid][n] = tb[(size_t)n * ID + tid];
    }

    // ---- phase 1: logits ----
    const int q = tid >> 3;   // i-thread: i0 = q*4
    const int r = tid & 7;    // n-thread: n0 = r*4
    float acc[4][4] = {{0.f}};
    const float* ub = u + ((size_t)b * IN + iBase) * ID;

    for (int kc = 0; kc < ID / 16; ++kc) {
        __syncthreads();   // Ts ready (first iter) / prior chunk consumed
#pragma unroll
        for (int rep = 0; rep < 2; ++rep) {
            const int f = tid + rep * 256;
            const int i = f >> 2, c4 = f & 3;
            const float4 v = *(const float4*)(ub + (size_t)i * ID + kc * 16 + c4 * 4);
            Us[c4 * 4 + 0][i] = v.x;
            Us[c4 * 4 + 1][i] = v.y;
            Us[c4 * 4 + 2][i] = v.z;
            Us[c4 * 4 + 3][i] = v.w;
        }
        __syncthreads();
#pragma unroll
        for (int k = 0; k < 16; ++k) {
            const float4 a4 = *(const float4*)&Us[k][q * 4];
            const float4 b4 = *(const float4*)&Ts[kc * 16 + k][r * 4];
            const float av[4] = {a4.x, a4.y, a4.z, a4.w};
            const float bv[4] = {b4.x, b4.y, b4.z, b4.w};
#pragma unroll
            for (int ii = 0; ii < 4; ++ii)
#pragma unroll
                for (int jj = 0; jj < 4; ++jj) acc[ii][jj] += av[ii] * bv[jj];
        }
    }

    // logits -> LDS
#pragma unroll
    for (int ii = 0; ii < 4; ++ii)
        *(float4*)&cl[q * 4 + ii][r * 4] =
            make_float4(acc[ii][0], acc[ii][1], acc[ii][2], acc[ii][3]);
    __syncthreads();

    // ---- phase 2: softmax over 32 n; 2 threads per i (16 n each) ----
    {
        const int i = tid >> 1, half = tid & 1;
        float v[16];
#pragma unroll
        for (int j = 0; j < 16; ++j) v[j] = cl[i][half * 16 + j];
        float mx = v[0];
#pragma unroll
        for (int j = 1; j < 16; ++j) mx = fmaxf(mx, v[j]);
        mx = fmaxf(mx, __shfl_xor(mx, 1));
        float sum = 0.f;
#pragma unroll
        for (int j = 0; j < 16; ++j) { v[j] = __expf(v[j] - mx); sum += v[j]; }
        sum += __shfl_xor(sum, 1);
        const float inv = 1.0f / sum;
#pragma unroll
        for (int j = 0; j < 16; ++j) cl[i][half * 16 + j] = v[j] * inv;
    }
    __syncthreads();

    // ---- phase 3: weighted aggregation (u tile re-read, L2-hot) ----
    const int d4 = tid & 63;       // float4 index into ID
    const int ng = tid >> 6;       // n base = ng*8 (wave-uniform -> LDS broadcast)
    float a2[8][4] = {{0.f}};
    const float* ur = ub + d4 * 4;
#pragma unroll 4
    for (int i = 0; i < RTILE; ++i) {
        const float4 uv = *(const float4*)(ur + (size_t)i * ID);
        const float4 c0 = *(const float4*)&cl[i][ng * 8];
        const float4 c1 = *(const float4*)&cl[i][ng * 8 + 4];
        const float cv[8] = {c0.x, c0.y, c0.z, c0.w, c1.x, c1.y, c1.z, c1.w};
        const float uvv[4] = {uv.x, uv.y, uv.z, uv.w};
#pragma unroll
        for (int j = 0; j < 8; ++j)
#pragma unroll
            for (int x = 0; x < 4; ++x) a2[j][x] += cv[j] * uvv[x];
    }

    float* spb = sp + (size_t)(it * B + b) * NC * ID;
#pragma unroll
    for (int j = 0; j < 8; ++j) {
        const int n = ng * 8 + j;
        *(float4*)&spb[(size_t)n * ID + d4 * 4] =
            make_float4(a2[j][0], a2[j][1], a2[j][2], a2[j][3]);
    }
}

// ---------------------------------------------------------------------------
extern "C" void kernel_launch(void* const* d_in, const int* in_sizes, int n_in,
                              void* d_out, int out_size, void* d_ws, size_t ws_size,
                              hipStream_t stream) {
    const float* u = (const float*)d_in[0];   // [B][IN][ID]
    const float* W = (const float*)d_in[1];   // [NC*DC][ID]
    float* out = (float*)d_out;               // [B][NC][DC]

    float* ws  = (float*)d_ws;
    float* t   = ws;                                   // B*NC*ID      = 0.5M floats
    float* sp  = t + (size_t)B * NC * ID;              // 8*B*NC*ID    = 4M floats
    float* sp0 = sp + (size_t)8 * B * NC * ID;         // 8*B*ID       = 128K floats

    const dim3 blk(256);

    // routing iteration 0 (c uniform = 1/32)
    k_sumu <<<dim3(8, B), blk, 0, stream>>>(u, sp0);
    k_ot   <<<dim3(NC * (B / 4)), blk, 0, stream>>>(W, sp0, t, 0);
    // iteration 1 (logits + softmax + aggregate fused)
    k_route<<<dim3(IN / RTILE, B), blk, 0, stream>>>(u, t, sp);
    k_ot   <<<dim3(NC * (B / 4)), blk, 0, stream>>>(W, sp, t, 1);
    // iteration 2
    k_route<<<dim3(IN / RTILE, B), blk, 0, stream>>>(u, t, sp);
    k_ot   <<<dim3(NC * (B / 4)), blk, 0, stream>>>(W, sp, out, 2);
}